// Round 15
// baseline (3029.716 us; speedup 1.0000x reference)
//
#include <hip/hip_runtime.h>
#include <math.h>

#define T_LEN 8192
#define NUM_CH 64
#define HID 256
#define NUM_CLS 40
#define NUM_PROP 1024
#define NUM_PROP_AFTER 256
#define PROP_LEN 128

#define MS 2        // sequences per group
#define NGRP 128    // sequence groups
#define NSL 2       // hidden slices (128 units each)
#define KH 320      // block-local kappa: [0,128) own-h, [128,192) x, [192,320) peer-h
#define HXPAR 65536 // u32s per parity buffer: 256 seqs x 256 units

typedef _Float16 h2_t __attribute__((ext_vector_type(2)));
union U32H2 { unsigned int u; h2_t h; };
union HU16 { _Float16 h; unsigned short u; };

#if defined(__has_builtin)
#if __has_builtin(__builtin_amdgcn_fdot2)
#define HAS_FDOT2 1
#endif
#endif

__device__ __forceinline__ float dot2f(unsigned int wa, unsigned int hb, float acc) {
    U32H2 a, b;
    a.u = wa;
    b.u = hb;
#ifdef HAS_FDOT2
    return __builtin_amdgcn_fdot2(a.h, b.h, acc, false);
#else
    return acc + (float)a.h[0] * (float)b.h[0] + (float)a.h[1] * (float)b.h[1];
#endif
}

__device__ __forceinline__ float dot8f(const uint4& w, const uint4& h, float acc) {
    acc = dot2f(w.x, h.x, acc);
    acc = dot2f(w.y, h.y, acc);
    acc = dot2f(w.z, h.z, acc);
    acc = dot2f(w.w, h.w, acc);
    return acc;
}

__device__ __forceinline__ float fsigmoid(float x) { return 1.0f / (1.0f + __expf(-x)); }
__device__ __forceinline__ float ftanh(float x) {
    float e = __expf(-2.0f * fabsf(x));
    float t = (1.0f - e) / (1.0f + e);
    return copysignf(t, x);
}

__device__ __forceinline__ unsigned int pack2(float a, float b) {
    HU16 ha, hb;
    ha.h = (_Float16)a;
    hb.h = (_Float16)b;
    return (unsigned int)ha.u | ((unsigned int)hb.u << 16);
}

__device__ __forceinline__ bool tag2ok(unsigned long long v, unsigned int tagv) {
    return ((unsigned int)v >> 16) == tagv &&
           ((unsigned int)(v >> 32) >> 16) == tagv;
}

// ---------------------------------------------------------------------------
// NSL=2 geometry (R7's architecture, spill FIXED via amdgpu_waves_per_eu(4,4)):
// 256 blocks = 2 slices x 128 groups of 2 seqs; W fragment = Wr[20] (80 VGPRs,
// 160 f16/thread) in kappa order. kseg = tid>>9: kseg0 = kappa[0,160) fully
// LOCAL (own-h 128 + x 32), kseg1 = kappa[160,320): 32 local x + 128 PEER.
// Exchange: R11/R14-verified tagged-u64 protocol, ONE peer block, 128 gather
// samples (waves 4-5, first probe issued before their local dot), LDS-flag
// gated peer-dot for kseg1. Publish: 128 u64 agent-scope stores (waves 0-3).
// ---------------------------------------------------------------------------
__global__ __launch_bounds__(1024)
__attribute__((amdgpu_waves_per_eu(4, 4))) void fused_kernel(
    const float* __restrict__ data, const float* __restrict__ prop,
    const float* __restrict__ W_ih, const float* __restrict__ W_hh,
    const float* __restrict__ b_ih, const float* __restrict__ b_hh,
    const float* __restrict__ W_cls, const float* __restrict__ b_cls,
    const float* __restrict__ W_bbox, const float* __restrict__ b_bbox,
    float* __restrict__ out, unsigned int* __restrict__ t0s,
    unsigned int* __restrict__ Hx32) {
    // smem: pp = [0,8192) floats [sq][kseg][512]; hx = [8192, 9472) 640 halves;
    // gfl at 9472. NMS (block 0) overlays [0, 13440) BEFORE hx/gfl init.
    __shared__ __align__(16) unsigned char smem[13568];
    float* pp = (float*)smem;
    _Float16* hx = (_Float16*)(smem + 8192);  // [sq*320 + kappa]
    volatile unsigned int* gfl = (volatile unsigned int*)(smem + 9472);

    const int tid = threadIdx.x;
    const int g = blockIdx.x & (NGRP - 1);   // group
    const int s = blockIdx.x >> 7;           // slice (units [128s, 128s+128))
    const int kseg = tid >> 9;               // wave-uniform K segment (0/1)
    const int row = tid & 511;               // gate*128 + unit
    const int wid = tid >> 6;

    // ===================== block 0: NMS (smem overlay) =====================
    if (blockIdx.x == 0) {
        float* sc_p = (float*)smem;
        float* ss = (float*)(smem + 4096);
        float* se = (float*)(smem + 8192);
        unsigned char* sup = smem + 12288;
        unsigned long long* cmask = (unsigned long long*)(smem + 13312);

        float ps = prop[tid * 3 + 0];
        float pe = prop[tid * 3 + 1];
        float pc = prop[tid * 3 + 2];
        sc_p[tid] = pc;
        sup[tid] = 0;
        __syncthreads();

        int r = 0;
        for (int j = 0; j < NUM_PROP; ++j) {
            float o = sc_p[j];
            r += (o > pc) || (o == pc && j < tid);
        }
        ss[r] = ps;
        se[r] = pe;
        __syncthreads();

        const float my_s = ss[tid];
        const float my_e = se[tid];
        const float my_len = my_e - my_s;
        bool mysup = false;

        for (int ci = 0; ci < 16; ++ci) {
            if (tid < 64) {
                int i = ci * 64 + tid;
                float is_ = ss[i], ie_ = se[i];
                unsigned long long m = __ballot(sup[i] != 0);
                for (int l = 0; l < 64; ++l) {
                    if (!((m >> l) & 1)) {
                        float ls = __shfl(is_, l);
                        float le = __shfl(ie_, l);
                        float inter = fmaxf(fminf(le, ie_) - fmaxf(ls, is_), 0.0f);
                        float uni = (le - ls) + (ie_ - is_) - inter;
                        float iou = inter / fmaxf(uni, 1e-6f);
                        unsigned long long nb = __ballot((tid > l) && (iou > 0.5f));
                        m |= nb;
                    }
                }
                sup[i] = (unsigned char)((m >> tid) & 1);
                if (tid == 0) cmask[ci] = ~m;
            }
            __syncthreads();
            unsigned long long am = cmask[ci];
            for (int l = 0; l < 64; ++l) {
                if ((am >> l) & 1) {
                    int i = ci * 64 + l;
                    if (tid > i && !mysup) {
                        float ls = ss[i], le = se[i];
                        float inter = fmaxf(fminf(le, my_e) - fmaxf(ls, my_s), 0.0f);
                        float uni = (le - ls) + my_len - inter;
                        if (inter / fmaxf(uni, 1e-6f) > 0.5f) mysup = true;
                    }
                }
            }
            sup[tid] = mysup ? 1 : 0;
            __syncthreads();
        }

        int myc = tid >> 6;
        unsigned long long mybit = 1ull << (tid & 63);
        int kb = 0, kt = 0;
        for (int c2 = 0; c2 < 16; ++c2) {
            int p = __popcll(cmask[c2]);
            kt += p;
            if (c2 < myc) kb += p;
        }
        kb += __popcll(cmask[myc] & (mybit - 1));
        int slot = (cmask[myc] & mybit) ? kb : (kt + (tid - kb));
        if (slot < NUM_PROP_AFTER) {
            int t0v = (int)rintf(my_s);
            t0v = max(0, min(t0v, T_LEN - PROP_LEN));
            __hip_atomic_store(&t0s[slot], (unsigned int)t0v | 0x80000000u,
                               __ATOMIC_RELAXED, __HIP_MEMORY_SCOPE_AGENT);
        }
        asm volatile("s_waitcnt vmcnt(0)" ::: "memory");
        __syncthreads();
    }

    // ===== W fragment in kappa order: Wr[20] = 160 halves of row (s,row) =====
    uint4 Wr[20];
    {
        const int gate = row >> 7, unit = row & 127;
        const int grow = gate * 256 + s * 128 + unit;
        const float* __restrict__ bh = W_hh + grow * HID;
        const float* __restrict__ bx = W_ih + grow * NUM_CH;
#pragma unroll
        for (int j = 0; j < 20; ++j) {
            const int kp = kseg * 160 + j * 8;  // kappa
            const float* src;
            if (kp < 128) {
                src = bh + s * 128 + kp;                    // own-slice h
            } else if (kp < 192) {
                src = bx + (kp - 128);                      // x
            } else {
                src = bh + (1 - s) * 128 + (kp - 192);      // peer-slice h
            }
            float4 f0 = *(const float4*)src;
            float4 f1 = *(const float4*)(src + 4);
            Wr[j] = make_uint4(pack2(f0.x, f0.y), pack2(f0.z, f0.w),
                               pack2(f1.x, f1.y), pack2(f1.z, f1.w));
        }
    }

    // producer role (tid<256): sq = tid>>7, u = tid&127 (unit of slice s)
    const int sq = tid >> 7;
    const int u = tid & 127;
    float bi = 0.f, bf = 0.f, bg = 0.f, bo = 0.f, c_st = 0.f;
    int xt0 = 0;
    if (tid < 256) {
        int gu = s * 128 + u;
        bi = b_ih[gu] + b_hh[gu];
        bf = b_ih[256 + gu] + b_hh[256 + gu];
        bg = b_ih[512 + gu] + b_hh[512 + gu];
        bo = b_ih[768 + gu] + b_hh[768 + gu];
    }

    // gather role (waves 4-5, tid 256..383): lane li -> one u64 = 2 tagged words
    const bool grole = (wid == 4 || wid == 5);
    const int li = tid - 256;                 // 0..127 when grole
    const int gsq = (li >> 6) & 1;            // seq
    const int pu = (li & 63) * 2;             // even unit within peer slice
    const int goff = (g * MS + gsq) * HID + (1 - s) * 128 + pu;  // even u32 idx

    // zero hx (640 halves) + flags
    if (tid < 640) ((unsigned short*)hx)[tid] = 0;
    if (tid < 2) gfl[tid] = 0;

    // producers with u<64 poll tagged t0s, load x(0) -> kappa [128,192)
    if (tid < 256 && u < 64) {
        const unsigned int* tp = &t0s[g * MS + sq];
        unsigned int tv;
        for (;;) {
            tv = __hip_atomic_load(tp, __ATOMIC_RELAXED, __HIP_MEMORY_SCOPE_AGENT);
            if (tv & 0x80000000u) break;
            __builtin_amdgcn_s_sleep(8);
        }
        xt0 = (int)(tv & 0x7FFFFFFFu);
        hx[sq * KH + 128 + u] = (_Float16)data[xt0 * NUM_CH + u];  // x(0)
    }
    __syncthreads();

    for (int t = 0; t < PROP_LEN; ++t) {
        // producers: early x(t+1) issue (lands during the dot)
        float xnext = 0.0f;
        if (tid < 256 && u < 64 && t + 1 < PROP_LEN)
            xnext = data[(xt0 + t + 1) * NUM_CH + u];

        // gather lanes: issue FIRST probe before the local dot (in flight under it)
        const unsigned int gtag = (unsigned int)t;
        const unsigned long long* ga =
            (const unsigned long long*)(Hx32 + (t & 1) * HXPAR + goff);
        unsigned long long gv = 0;
        if (grole && t >= 1)
            gv = __hip_atomic_load(ga, __ATOMIC_RELAXED, __HIP_MEMORY_SCOPE_AGENT);

        float a0 = 0.f, a1 = 0.f;
#define DOTJ(J)                                                         \
        {                                                               \
            const int hb = kseg * 160 + (J) * 8;                        \
            uint4 h0 = *(const uint4*)&hx[hb];                          \
            uint4 h1 = *(const uint4*)&hx[KH + hb];                     \
            uint4 w = Wr[(J)];                                          \
            a0 = dot8f(w, h0, a0);                                      \
            a1 = dot8f(w, h1, a1);                                      \
        }

        if (kseg == 0) {
            // --- fully local dot: kappa [0,160) ---
            DOTJ(0) DOTJ(1) DOTJ(2) DOTJ(3) DOTJ(4)
            DOTJ(5) DOTJ(6) DOTJ(7) DOTJ(8) DOTJ(9)
            DOTJ(10) DOTJ(11) DOTJ(12) DOTJ(13) DOTJ(14)
            DOTJ(15) DOTJ(16) DOTJ(17) DOTJ(18) DOTJ(19)
            // --- gather lanes finish the poll, stage peer h(t), set flag ---
            if (grole && t >= 1) {
                while (__builtin_expect(!tag2ok(gv, gtag), 0)) {
                    __builtin_amdgcn_s_sleep(2);
                    gv = __hip_atomic_load(ga, __ATOMIC_RELAXED,
                                           __HIP_MEMORY_SCOPE_AGENT);
                }
                unsigned int lo = (unsigned int)gv;
                unsigned int hi = (unsigned int)(gv >> 32);
                *(unsigned int*)&hx[gsq * KH + 192 + pu] =
                    (lo & 0xFFFFu) | (hi << 16);
                asm volatile("s_waitcnt lgkmcnt(0)" ::: "memory");
                if ((tid & 63) == 0) gfl[wid - 4] = (unsigned int)t;
            }
        } else {
            // --- local tail: kappa [160,192) = x[32,64) ---
            DOTJ(0) DOTJ(1) DOTJ(2) DOTJ(3)
            // --- wait for peer-h in LDS ---
            if (t >= 1) {
                while (gfl[0] < (unsigned int)t || gfl[1] < (unsigned int)t) {
                    __builtin_amdgcn_s_sleep(1);
                }
                asm volatile("" ::: "memory");
            }
            // --- peer dot: kappa [192,320) ---
            DOTJ(4) DOTJ(5) DOTJ(6) DOTJ(7) DOTJ(8)
            DOTJ(9) DOTJ(10) DOTJ(11) DOTJ(12) DOTJ(13)
            DOTJ(14) DOTJ(15) DOTJ(16) DOTJ(17) DOTJ(18) DOTJ(19)
        }
#undef DOTJ

        pp[(0 * 2 + kseg) * 512 + row] = a0;
        pp[(1 * 2 + kseg) * 512 + row] = a1;
        __syncthreads();  // B1

        const unsigned int tagv = (unsigned int)(t + 1);
        const int par = (t + 1) & 1;
        if (tid < 256) {
            // --- reduce (8 reads) + activation + PAIRED tagged publish ---
            float si = pp[(sq * 2 + 0) * 512 + u] + pp[(sq * 2 + 1) * 512 + u] + bi;
            float sf = pp[(sq * 2 + 0) * 512 + 128 + u] +
                       pp[(sq * 2 + 1) * 512 + 128 + u] + bf;
            float sg = pp[(sq * 2 + 0) * 512 + 256 + u] +
                       pp[(sq * 2 + 1) * 512 + 256 + u] + bg;
            float so = pp[(sq * 2 + 0) * 512 + 384 + u] +
                       pp[(sq * 2 + 1) * 512 + 384 + u] + bo;
            float gi = fsigmoid(si), gf = fsigmoid(sf);
            float gg = ftanh(sg), go = fsigmoid(so);
            c_st = gf * c_st + gi * gg;
            float h = go * ftanh(c_st);
            HU16 hu;
            hu.h = (_Float16)h;
            unsigned int myw = (tagv << 16) | (unsigned int)hu.u;
            unsigned int pw = __shfl_xor(myw, 1);
            if ((u & 1) == 0) {
                unsigned long long dw =
                    (unsigned long long)myw | ((unsigned long long)pw << 32);
                __hip_atomic_store(
                    (unsigned long long*)&Hx32[par * HXPAR +
                                               (g * MS + sq) * HID + s * 128 + u],
                    dw, __ATOMIC_RELAXED, __HIP_MEMORY_SCOPE_AGENT);
            }
            hx[sq * KH + u] = hu.h;  // own-h, kappa [0,128)
            if (u < 64 && t + 1 < PROP_LEN)
                hx[sq * KH + 128 + u] = (_Float16)xnext;  // x(t+1)
        }
        __syncthreads();  // B2
    }

    // final gather: peer h(128) (tag 128, parity 0) for the heads
    if (grole) {
        const unsigned int tagv = (unsigned int)PROP_LEN;
        const unsigned long long* ga = (const unsigned long long*)(Hx32 + goff);
        unsigned long long v =
            __hip_atomic_load(ga, __ATOMIC_RELAXED, __HIP_MEMORY_SCOPE_AGENT);
        while (!tag2ok(v, tagv)) {
            __builtin_amdgcn_s_sleep(2);
            v = __hip_atomic_load(ga, __ATOMIC_RELAXED, __HIP_MEMORY_SCOPE_AGENT);
        }
        unsigned int lo = (unsigned int)v;
        unsigned int hi = (unsigned int)(v >> 32);
        *(unsigned int*)&hx[gsq * KH + 192 + pu] = (lo & 0xFFFFu) | (hi << 16);
    }
    __syncthreads();

    // heads: slice s covers rows m in [60s, 60s+60) for its 2 seqs.
    // hx kappa: own units at [0,128) (global s*128+k), peer at [192,320)
    if (tid < MS * 60) {
        int hsq = tid / 60;
        int ml = tid % 60;
        int m = s * 60 + ml;
        int seqg = g * MS + hsq;
        const float* Wrow;
        float acc;
        int oidx;
        if (m < NUM_CLS) {
            Wrow = W_cls + m * HID;
            acc = b_cls[m];
            oidx = seqg * NUM_CLS + m;
        } else {
            int mb = m - NUM_CLS;
            Wrow = W_bbox + mb * HID;
            acc = b_bbox[mb];
            oidx = NUM_PROP_AFTER * NUM_CLS + seqg * 2 * NUM_CLS + mb;
        }
        const _Float16* hp = &hx[hsq * KH];
        for (int k = 0; k < 128; ++k) acc += Wrow[s * 128 + k] * (float)hp[k];
        for (int k = 0; k < 128; ++k)
            acc += Wrow[(1 - s) * 128 + k] * (float)hp[192 + k];
        out[oidx] = acc;
    }
}

extern "C" void kernel_launch(void* const* d_in, const int* in_sizes, int n_in,
                              void* d_out, int out_size, void* d_ws,
                              size_t ws_size, hipStream_t stream) {
    const float* data = (const float*)d_in[0];     // [8192, 64]
    const float* prop = (const float*)d_in[1];     // [1024, 3]
    const float* W_ih = (const float*)d_in[2];     // [1024, 64]
    const float* W_hh = (const float*)d_in[3];     // [1024, 256]
    const float* b_ih = (const float*)d_in[4];     // [1024]
    const float* b_hh = (const float*)d_in[5];     // [1024]
    const float* W_cls = (const float*)d_in[6];    // [40, 256]
    const float* b_cls = (const float*)d_in[7];    // [40]
    const float* W_bbox = (const float*)d_in[8];   // [80, 256]
    const float* b_bbox = (const float*)d_in[9];   // [80]
    float* out = (float*)d_out;

    // workspace layout (identical to R14)
    unsigned int* t0s = (unsigned int*)d_ws;                   // [0, 1KB) tagged t0s
    unsigned int* Hx32 = (unsigned int*)((char*)d_ws + 4096);  // 512 KB tagged h (2 parities)

    // zero all tags each invocation (graph-captured, replayed per rep)
    hipMemsetAsync(d_ws, 0, 4096 + 2 * HXPAR * 4, stream);

    void* kargs[] = {(void*)&data,  (void*)&prop,   (void*)&W_ih,  (void*)&W_hh,
                     (void*)&b_ih,  (void*)&b_hh,   (void*)&W_cls, (void*)&b_cls,
                     (void*)&W_bbox, (void*)&b_bbox, (void*)&out,  (void*)&t0s,
                     (void*)&Hx32};
    hipLaunchCooperativeKernel((void*)fused_kernel, dim3(NSL * NGRP), dim3(1024),
                               kargs, 0, stream);
}

// Round 16
// 628.709 us; speedup vs baseline: 4.8189x; 4.8189x over previous
//
#include <hip/hip_runtime.h>
#include <math.h>

#define T_LEN 8192
#define NUM_CH 64
#define HID 256
#define NUM_CLS 40
#define NUM_PROP 1024
#define NUM_PROP_AFTER 256
#define PROP_LEN 128

#define MS 4        // sequences per group
#define NGRP 64     // sequence groups (NUM_PROP_AFTER / MS)
#define NSL 4       // hidden slices (64 units each)
#define KH 320      // block-local kappa: [0,64) own-h, [64,128) x, [128,320) peer-h
#define KSEGN 4     // K segments per row
#define SEGH 80     // halves per segment
#define HXPAR 65536 // u32s per parity buffer: 256 seqs x 256 units

typedef _Float16 h2_t __attribute__((ext_vector_type(2)));
union U32H2 { unsigned int u; h2_t h; };
union HU16 { _Float16 h; unsigned short u; };

#if defined(__has_builtin)
#if __has_builtin(__builtin_amdgcn_fdot2)
#define HAS_FDOT2 1
#endif
#endif

__device__ __forceinline__ float dot2f(unsigned int wa, unsigned int hb, float acc) {
    U32H2 a, b;
    a.u = wa;
    b.u = hb;
#ifdef HAS_FDOT2
    return __builtin_amdgcn_fdot2(a.h, b.h, acc, false);
#else
    return acc + (float)a.h[0] * (float)b.h[0] + (float)a.h[1] * (float)b.h[1];
#endif
}

__device__ __forceinline__ float dot8f(const uint4& w, const uint4& h, float acc) {
    acc = dot2f(w.x, h.x, acc);
    acc = dot2f(w.y, h.y, acc);
    acc = dot2f(w.z, h.z, acc);
    acc = dot2f(w.w, h.w, acc);
    return acc;
}

__device__ __forceinline__ float fsigmoid(float x) { return 1.0f / (1.0f + __expf(-x)); }
__device__ __forceinline__ float ftanh(float x) {
    float e = __expf(-2.0f * fabsf(x));
    float t = (1.0f - e) / (1.0f + e);
    return copysignf(t, x);
}

__device__ __forceinline__ unsigned int pack2(float a, float b) {
    HU16 ha, hb;
    ha.h = (_Float16)a;
    hb.h = (_Float16)b;
    return (unsigned int)ha.u | ((unsigned int)hb.u << 16);
}

// ---------------------------------------------------------------------------
// R14 FINAL (verified best: 558us kernel / 621.5us total, passed twice):
// 256 blocks = 4 hid-slices x 64 seq-groups; W slice in VGPRs (Wr[10], kappa
// order); single fused cooperative launch (NMS in block 0); sound tagged-u64
// h-exchange (tag=t, parity dbuf, agent-scope relaxed — correctness never
// depends on timing/placement); split-dot overlap: kseg0 fully-local dot and
// gather waves' peer-fetch run concurrently, kseg1..3 peer-dots gated by LDS
// flags. 2 barriers/step.
// Refuted alternatives (this session): extra sync hops (R3/R9), phase-split
// (R6), u64-batching-only (R10 neutral), counter-only ordering (R8 UNSOUND),
// plain-store/sc0 L2 fast path (R13: stale data, never visible), NSL=2
// 80-VGPR geometry (R7/R15: compiler pins 64 VGPR at 16 waves -> spill).
// ---------------------------------------------------------------------------
__global__ __launch_bounds__(1024, 4) void fused_kernel(
    const float* __restrict__ data, const float* __restrict__ prop,
    const float* __restrict__ W_ih, const float* __restrict__ W_hh,
    const float* __restrict__ b_ih, const float* __restrict__ b_hh,
    const float* __restrict__ W_cls, const float* __restrict__ b_cls,
    const float* __restrict__ W_bbox, const float* __restrict__ b_bbox,
    float* __restrict__ out, unsigned int* __restrict__ t0s,
    unsigned int* __restrict__ Hx32) {
    __shared__ __align__(16) _Float16 hx[MS][KH];       // 2.5 KB (kappa layout)
    __shared__ __align__(16) float pp[MS][KSEGN][256];  // 16 KB (NMS overlay)
    __shared__ volatile unsigned int gfl[6];            // gather-wave flags

    const int tid = threadIdx.x;
    const int g = blockIdx.x & (NGRP - 1);
    const int s = blockIdx.x >> 6;
    const int kseg = tid >> 8;   // wave-uniform K segment
    const int rl = tid & 255;    // row_local = gate*64 + unit

    // ===================== block 0: NMS =====================
    if (blockIdx.x == 0) {
        float* sc_p = &pp[0][0][0];
        float* ss = &pp[1][0][0];
        float* se = &pp[2][0][0];
        unsigned char* sup = (unsigned char*)&pp[3][0][0];
        unsigned long long* cmask =
            (unsigned long long*)((char*)&pp[3][0][0] + 1024);

        float ps = prop[tid * 3 + 0];
        float pe = prop[tid * 3 + 1];
        float pc = prop[tid * 3 + 2];
        sc_p[tid] = pc;
        sup[tid] = 0;
        __syncthreads();

        int r = 0;
        for (int j = 0; j < NUM_PROP; ++j) {
            float o = sc_p[j];
            r += (o > pc) || (o == pc && j < tid);
        }
        ss[r] = ps;
        se[r] = pe;
        __syncthreads();

        const float my_s = ss[tid];
        const float my_e = se[tid];
        const float my_len = my_e - my_s;
        bool mysup = false;

        for (int ci = 0; ci < 16; ++ci) {
            if (tid < 64) {
                int i = ci * 64 + tid;
                float is_ = ss[i], ie_ = se[i];
                unsigned long long m = __ballot(sup[i] != 0);
                for (int l = 0; l < 64; ++l) {
                    if (!((m >> l) & 1)) {
                        float ls = __shfl(is_, l);
                        float le = __shfl(ie_, l);
                        float inter = fmaxf(fminf(le, ie_) - fmaxf(ls, is_), 0.0f);
                        float uni = (le - ls) + (ie_ - is_) - inter;
                        float iou = inter / fmaxf(uni, 1e-6f);
                        unsigned long long nb = __ballot((tid > l) && (iou > 0.5f));
                        m |= nb;
                    }
                }
                sup[i] = (unsigned char)((m >> tid) & 1);
                if (tid == 0) cmask[ci] = ~m;
            }
            __syncthreads();
            unsigned long long am = cmask[ci];
            for (int l = 0; l < 64; ++l) {
                if ((am >> l) & 1) {
                    int i = ci * 64 + l;
                    if (tid > i && !mysup) {
                        float ls = ss[i], le = se[i];
                        float inter = fmaxf(fminf(le, my_e) - fmaxf(ls, my_s), 0.0f);
                        float uni = (le - ls) + my_len - inter;
                        if (inter / fmaxf(uni, 1e-6f) > 0.5f) mysup = true;
                    }
                }
            }
            sup[tid] = mysup ? 1 : 0;
            __syncthreads();
        }

        int myc = tid >> 6;
        unsigned long long mybit = 1ull << (tid & 63);
        int kb = 0, kt = 0;
        for (int c2 = 0; c2 < 16; ++c2) {
            int p = __popcll(cmask[c2]);
            kt += p;
            if (c2 < myc) kb += p;
        }
        kb += __popcll(cmask[myc] & (mybit - 1));
        int slot = (cmask[myc] & mybit) ? kb : (kt + (tid - kb));
        if (slot < NUM_PROP_AFTER) {
            int t0v = (int)rintf(my_s);
            t0v = max(0, min(t0v, T_LEN - PROP_LEN));
            __hip_atomic_store(&t0s[slot], (unsigned int)t0v | 0x80000000u,
                               __ATOMIC_RELAXED, __HIP_MEMORY_SCOPE_AGENT);
        }
        asm volatile("s_waitcnt vmcnt(0)" ::: "memory");
        __syncthreads();
    }

    // ===== W fragment in kappa order: Wr[10] = 80 halves of row (s,rl) =====
    uint4 Wr[10];
    {
        const int gate = rl >> 6, unit = rl & 63;
        const int grow = gate * 256 + s * 64 + unit;
        const float* __restrict__ bh = W_hh + grow * HID;
        const float* __restrict__ bx = W_ih + grow * NUM_CH;
#pragma unroll
        for (int j = 0; j < 10; ++j) {
            const int kp = kseg * SEGH + j * 8;  // kappa
            const float* src;
            if (kp < 64) {
                src = bh + s * 64 + kp;                     // own-slice h
            } else if (kp < 128) {
                src = bx + (kp - 64);                       // x
            } else {
                int q = (kp - 128) >> 6, v = (kp - 128) & 63;
                int sp = q + (q >= s ? 1 : 0);
                src = bh + sp * 64 + v;                     // peer-slice h
            }
            float4 f0 = *(const float4*)src;
            float4 f1 = *(const float4*)(src + 4);
            Wr[j] = make_uint4(pack2(f0.x, f0.y), pack2(f0.z, f0.w),
                               pack2(f1.x, f1.y), pack2(f1.z, f1.w));
        }
    }

    // producer role (tid<256): wave aq = seq, lane au = unit of slice s
    const int aq = tid >> 6;
    const int au = tid & 63;
    float bi = 0.f, bf = 0.f, bg = 0.f, bo = 0.f, c_st = 0.f;
    int xt0 = 0;
    if (tid < 256) {
        int u = s * 64 + au;
        bi = b_ih[u] + b_hh[u];
        bf = b_ih[256 + u] + b_hh[256 + u];
        bg = b_ih[512 + u] + b_hh[512 + u];
        bo = b_ih[768 + u] + b_hh[768 + u];
    }

    // gather role (waves 8-13, tid 512..895): lane li, one u64 = 2 tagged words
    const int li = tid - 512;                 // 0..383
    const int q_ = li >> 7;                   // peer index 0..2
    const int rem = li & 127;
    const int gsq = rem >> 5;                 // seq
    const int gu2 = (rem & 31) * 2;           // even unit within peer slice
    const int sp_ = q_ + (q_ >= s ? 1 : 0);   // peer slice
    const int goff = (g * MS + gsq) * HID + sp_ * 64 + gu2;  // even u32 index
    const int gw = (tid >> 6) - 8;            // gather wave id 0..5

    // zero hx (1280 halves) + flags
    ((unsigned short*)hx)[tid] = 0;
    if (tid < 256) ((unsigned short*)hx)[1024 + tid] = 0;
    if (tid < 6) gfl[tid] = 0;

    // producers poll tagged t0s, load x(0) -> kappa [64,128)
    if (tid < 256) {
        const unsigned int* tp = &t0s[g * MS + aq];
        unsigned int tv;
        for (;;) {
            tv = __hip_atomic_load(tp, __ATOMIC_RELAXED, __HIP_MEMORY_SCOPE_AGENT);
            if (tv & 0x80000000u) break;
            __builtin_amdgcn_s_sleep(8);
        }
        xt0 = (int)(tv & 0x7FFFFFFFu);
        hx[aq][64 + au] = (_Float16)data[xt0 * NUM_CH + au];  // x(0)
    }
    __syncthreads();

    for (int t = 0; t < PROP_LEN; ++t) {
        // producers: early x(t+1) issue (lands during the dot)
        float xnext = 0.0f;
        if (tid < 256 && t + 1 < PROP_LEN)
            xnext = data[(xt0 + t + 1) * NUM_CH + au];

        float a0 = 0.f, a1 = 0.f, a2 = 0.f, a3 = 0.f;
#define DOTJ(J)                                                         \
        {                                                               \
            const int hb = kseg * SEGH + (J) * 8;                       \
            uint4 h0 = *(const uint4*)&hx[0][hb];                       \
            uint4 h1 = *(const uint4*)&hx[1][hb];                       \
            uint4 h2 = *(const uint4*)&hx[2][hb];                       \
            uint4 h3 = *(const uint4*)&hx[3][hb];                       \
            uint4 w = Wr[(J)];                                          \
            a0 = dot8f(w, h0, a0);                                      \
            a1 = dot8f(w, h1, a1);                                      \
            a2 = dot8f(w, h2, a2);                                      \
            a3 = dot8f(w, h3, a3);                                      \
        }

        // --- phase 1: local dot (kseg0: all 10; kseg1: first 6) ---
        if (kseg == 0) {
            DOTJ(0) DOTJ(1) DOTJ(2) DOTJ(3) DOTJ(4)
            DOTJ(5) DOTJ(6) DOTJ(7) DOTJ(8) DOTJ(9)
        } else if (kseg == 1) {
            DOTJ(0) DOTJ(1) DOTJ(2) DOTJ(3) DOTJ(4) DOTJ(5)
        }

        // --- gather peer h(t) (waves 8-13), concurrent with local dots ---
        if (t >= 1 && tid >= 512 && tid < 896) {
            const unsigned int tagv = (unsigned int)t;
            const int par = t & 1;
            const unsigned long long* ga =
                (const unsigned long long*)(Hx32 + par * HXPAR + goff);
            unsigned long long v =
                __hip_atomic_load(ga, __ATOMIC_RELAXED, __HIP_MEMORY_SCOPE_AGENT);
            while (__builtin_expect(((unsigned int)v >> 16) != tagv ||
                                        ((unsigned int)(v >> 32) >> 16) != tagv,
                                    0)) {
                __builtin_amdgcn_s_sleep(2);
                v = __hip_atomic_load(ga, __ATOMIC_RELAXED,
                                      __HIP_MEMORY_SCOPE_AGENT);
            }
            unsigned int lo = (unsigned int)v;
            unsigned int hi = (unsigned int)(v >> 32);
            *(unsigned int*)&hx[gsq][128 + q_ * 64 + gu2] =
                (lo & 0xFFFFu) | (hi << 16);
            asm volatile("s_waitcnt lgkmcnt(0)" ::: "memory");
            if ((tid & 63) == 0) gfl[gw] = (unsigned int)t;
        }

        // --- flag wait, then peer dot (kseg >= 1) ---
        if (kseg != 0) {
            if (t >= 1) {
                while (gfl[0] < (unsigned int)t || gfl[1] < (unsigned int)t ||
                       gfl[2] < (unsigned int)t || gfl[3] < (unsigned int)t ||
                       gfl[4] < (unsigned int)t || gfl[5] < (unsigned int)t) {
                    __builtin_amdgcn_s_sleep(1);
                }
                asm volatile("" ::: "memory");
            }
            if (kseg == 1) {
                DOTJ(6) DOTJ(7) DOTJ(8) DOTJ(9)
            } else {
                DOTJ(0) DOTJ(1) DOTJ(2) DOTJ(3) DOTJ(4)
                DOTJ(5) DOTJ(6) DOTJ(7) DOTJ(8) DOTJ(9)
            }
        }
#undef DOTJ

        pp[0][kseg][rl] = a0;
        pp[1][kseg][rl] = a1;
        pp[2][kseg][rl] = a2;
        pp[3][kseg][rl] = a3;
        __syncthreads();  // B1

        const unsigned int tagv = (unsigned int)(t + 1);
        const int par = (t + 1) & 1;
        if (tid < 256) {
            // --- reduce + activation + PAIRED tagged publish + local writes ---
            float si = pp[aq][0][au] + pp[aq][1][au] + pp[aq][2][au] +
                       pp[aq][3][au] + bi;
            float sf = pp[aq][0][64 + au] + pp[aq][1][64 + au] +
                       pp[aq][2][64 + au] + pp[aq][3][64 + au] + bf;
            float sg = pp[aq][0][128 + au] + pp[aq][1][128 + au] +
                       pp[aq][2][128 + au] + pp[aq][3][128 + au] + bg;
            float so = pp[aq][0][192 + au] + pp[aq][1][192 + au] +
                       pp[aq][2][192 + au] + pp[aq][3][192 + au] + bo;
            float gi = fsigmoid(si), gf = fsigmoid(sf);
            float gg = ftanh(sg), go = fsigmoid(so);
            c_st = gf * c_st + gi * gg;
            float h = go * ftanh(c_st);
            HU16 hu;
            hu.h = (_Float16)h;
            unsigned int myw = (tagv << 16) | (unsigned int)hu.u;
            unsigned int pw = __shfl_xor(myw, 1);
            if ((au & 1) == 0) {
                unsigned long long dw =
                    (unsigned long long)myw | ((unsigned long long)pw << 32);
                __hip_atomic_store(
                    (unsigned long long*)&Hx32[par * HXPAR +
                                               (g * MS + aq) * HID + s * 64 + au],
                    dw, __ATOMIC_RELAXED, __HIP_MEMORY_SCOPE_AGENT);
            }
            hx[aq][au] = hu.h;                                  // own-h, kappa [0,64)
            if (t + 1 < PROP_LEN) hx[aq][64 + au] = (_Float16)xnext;  // x(t+1)
        }
        __syncthreads();  // B2
    }

    // final gather: peer h(128) (tag 128, parity 0) for the heads
    if (tid >= 512 && tid < 896) {
        const unsigned int tagv = (unsigned int)PROP_LEN;
        const unsigned long long* ga = (const unsigned long long*)(Hx32 + goff);
        unsigned long long v =
            __hip_atomic_load(ga, __ATOMIC_RELAXED, __HIP_MEMORY_SCOPE_AGENT);
        while (((unsigned int)v >> 16) != tagv ||
               ((unsigned int)(v >> 32) >> 16) != tagv) {
            __builtin_amdgcn_s_sleep(2);
            v = __hip_atomic_load(ga, __ATOMIC_RELAXED, __HIP_MEMORY_SCOPE_AGENT);
        }
        unsigned int lo = (unsigned int)v;
        unsigned int hi = (unsigned int)(v >> 32);
        *(unsigned int*)&hx[gsq][128 + q_ * 64 + gu2] = (lo & 0xFFFFu) | (hi << 16);
    }
    __syncthreads();

    // heads: hx kappa layout: own [0,64), peers q at [128+q*64, ...)
    if (tid < MS * 30) {
        int sq = tid / 30;
        int ml = tid % 30;
        int m = s * 30 + ml;
        const float* Wrow;
        float acc;
        int oidx;
        if (m < NUM_CLS) {
            Wrow = W_cls + m * HID;
            acc = b_cls[m];
            oidx = (g * MS + sq) * NUM_CLS + m;
        } else {
            int mb = m - NUM_CLS;
            Wrow = W_bbox + mb * HID;
            acc = b_bbox[mb];
            oidx = NUM_PROP_AFTER * NUM_CLS + (g * MS + sq) * 2 * NUM_CLS + mb;
        }
        const _Float16* hp = &hx[sq][0];
        for (int k = 0; k < 64; ++k) acc += Wrow[s * 64 + k] * (float)hp[k];
        for (int q2 = 0; q2 < 3; ++q2) {
            int sp2 = q2 + (q2 >= s ? 1 : 0);
            const float* wr = Wrow + sp2 * 64;
            const _Float16* hr = hp + 128 + q2 * 64;
            for (int v2 = 0; v2 < 64; ++v2) acc += wr[v2] * (float)hr[v2];
        }
        out[oidx] = acc;
    }
}

extern "C" void kernel_launch(void* const* d_in, const int* in_sizes, int n_in,
                              void* d_out, int out_size, void* d_ws,
                              size_t ws_size, hipStream_t stream) {
    const float* data = (const float*)d_in[0];     // [8192, 64]
    const float* prop = (const float*)d_in[1];     // [1024, 3]
    const float* W_ih = (const float*)d_in[2];     // [1024, 64]
    const float* W_hh = (const float*)d_in[3];     // [1024, 256]
    const float* b_ih = (const float*)d_in[4];     // [1024]
    const float* b_hh = (const float*)d_in[5];     // [1024]
    const float* W_cls = (const float*)d_in[6];    // [40, 256]
    const float* b_cls = (const float*)d_in[7];    // [40]
    const float* W_bbox = (const float*)d_in[8];   // [80, 256]
    const float* b_bbox = (const float*)d_in[9];   // [80]
    float* out = (float*)d_out;

    // workspace layout (identical to R10/R11/R14)
    unsigned int* t0s = (unsigned int*)d_ws;                   // [0, 1KB) tagged t0s
    unsigned int* Hx32 = (unsigned int*)((char*)d_ws + 4096);  // 512 KB tagged h (2 parities)

    // zero all tags each invocation (graph-captured, replayed per rep)
    hipMemsetAsync(d_ws, 0, 4096 + 2 * HXPAR * 4, stream);

    void* kargs[] = {(void*)&data,  (void*)&prop,   (void*)&W_ih,  (void*)&W_hh,
                     (void*)&b_ih,  (void*)&b_hh,   (void*)&W_cls, (void*)&b_cls,
                     (void*)&W_bbox, (void*)&b_bbox, (void*)&out,  (void*)&t0s,
                     (void*)&Hx32};
    hipLaunchCooperativeKernel((void*)fused_kernel, dim3(NSL * NGRP), dim3(1024),
                               kargs, 0, stream);
}

// Round 17
// 620.872 us; speedup vs baseline: 4.8798x; 1.0126x over previous
//
#include <hip/hip_runtime.h>
#include <math.h>

#define T_LEN 8192
#define NUM_CH 64
#define HID 256
#define NUM_CLS 40
#define NUM_PROP 1024
#define NUM_PROP_AFTER 256
#define PROP_LEN 128

#define MS 4        // sequences per group
#define NGRP 64     // sequence groups (NUM_PROP_AFTER / MS)
#define NSL 4       // hidden slices (64 units each)
#define KH 320      // block-local kappa: [0,64) own-h, [64,128) x, [128,320) peer-h
#define KSEGN 4     // K segments per row
#define SEGH 80     // halves per segment
#define HXPAR 65536 // u32s per parity buffer: 256 seqs x 256 units

typedef _Float16 h2_t __attribute__((ext_vector_type(2)));
union U32H2 { unsigned int u; h2_t h; };
union HU16 { _Float16 h; unsigned short u; };

#if defined(__has_builtin)
#if __has_builtin(__builtin_amdgcn_fdot2)
#define HAS_FDOT2 1
#endif
#endif

__device__ __forceinline__ float dot2f(unsigned int wa, unsigned int hb, float acc) {
    U32H2 a, b;
    a.u = wa;
    b.u = hb;
#ifdef HAS_FDOT2
    return __builtin_amdgcn_fdot2(a.h, b.h, acc, false);
#else
    return acc + (float)a.h[0] * (float)b.h[0] + (float)a.h[1] * (float)b.h[1];
#endif
}

__device__ __forceinline__ float dot8f(const uint4& w, const uint4& h, float acc) {
    acc = dot2f(w.x, h.x, acc);
    acc = dot2f(w.y, h.y, acc);
    acc = dot2f(w.z, h.z, acc);
    acc = dot2f(w.w, h.w, acc);
    return acc;
}

__device__ __forceinline__ float fsigmoid(float x) { return 1.0f / (1.0f + __expf(-x)); }
__device__ __forceinline__ float ftanh(float x) {
    float e = __expf(-2.0f * fabsf(x));
    float t = (1.0f - e) / (1.0f + e);
    return copysignf(t, x);
}

__device__ __forceinline__ unsigned int pack2(float a, float b) {
    HU16 ha, hb;
    ha.h = (_Float16)a;
    hb.h = (_Float16)b;
    return (unsigned int)ha.u | ((unsigned int)hb.u << 16);
}

// ---------------------------------------------------------------------------
// R16 base (verified 3x: 554-558us kernel / 621-629us total) + INCREMENTAL NMS
// SLOT PUBLISH: after chunk ci's resolution barrier, proposals in chunk ci
// have FINAL greedy status and their slot index (alive-prefix popcount) is
// determined -> publish tagged t0s[slot] immediately instead of after all 16
// chunks. LSTM groups with early slots start ~20us sooner. Final catch-all
// publish kept verbatim (suppressed-fill when kept<256; alive re-publish is
// idempotent). Consumers unchanged: tag validation is the only gate.
// ---------------------------------------------------------------------------
__global__ __launch_bounds__(1024, 4) void fused_kernel(
    const float* __restrict__ data, const float* __restrict__ prop,
    const float* __restrict__ W_ih, const float* __restrict__ W_hh,
    const float* __restrict__ b_ih, const float* __restrict__ b_hh,
    const float* __restrict__ W_cls, const float* __restrict__ b_cls,
    const float* __restrict__ W_bbox, const float* __restrict__ b_bbox,
    float* __restrict__ out, unsigned int* __restrict__ t0s,
    unsigned int* __restrict__ Hx32) {
    __shared__ __align__(16) _Float16 hx[MS][KH];       // 2.5 KB (kappa layout)
    __shared__ __align__(16) float pp[MS][KSEGN][256];  // 16 KB (NMS overlay)
    __shared__ volatile unsigned int gfl[6];            // gather-wave flags

    const int tid = threadIdx.x;
    const int g = blockIdx.x & (NGRP - 1);
    const int s = blockIdx.x >> 6;
    const int kseg = tid >> 8;   // wave-uniform K segment
    const int rl = tid & 255;    // row_local = gate*64 + unit

    // ===================== block 0: NMS =====================
    if (blockIdx.x == 0) {
        float* sc_p = &pp[0][0][0];
        float* ss = &pp[1][0][0];
        float* se = &pp[2][0][0];
        unsigned char* sup = (unsigned char*)&pp[3][0][0];
        unsigned long long* cmask =
            (unsigned long long*)((char*)&pp[3][0][0] + 1024);

        float ps = prop[tid * 3 + 0];
        float pe = prop[tid * 3 + 1];
        float pc = prop[tid * 3 + 2];
        sc_p[tid] = pc;
        sup[tid] = 0;
        __syncthreads();

        int r = 0;
        for (int j = 0; j < NUM_PROP; ++j) {
            float o = sc_p[j];
            r += (o > pc) || (o == pc && j < tid);
        }
        ss[r] = ps;
        se[r] = pe;
        __syncthreads();

        const float my_s = ss[tid];
        const float my_e = se[tid];
        const float my_len = my_e - my_s;
        const int myc = tid >> 6;
        const unsigned long long mybit = 1ull << (tid & 63);
        bool mysup = false;

        for (int ci = 0; ci < 16; ++ci) {
            if (tid < 64) {
                int i = ci * 64 + tid;
                float is_ = ss[i], ie_ = se[i];
                unsigned long long m = __ballot(sup[i] != 0);
                for (int l = 0; l < 64; ++l) {
                    if (!((m >> l) & 1)) {
                        float ls = __shfl(is_, l);
                        float le = __shfl(ie_, l);
                        float inter = fmaxf(fminf(le, ie_) - fmaxf(ls, is_), 0.0f);
                        float uni = (le - ls) + (ie_ - is_) - inter;
                        float iou = inter / fmaxf(uni, 1e-6f);
                        unsigned long long nb = __ballot((tid > l) && (iou > 0.5f));
                        m |= nb;
                    }
                }
                sup[i] = (unsigned char)((m >> tid) & 1);
                if (tid == 0) cmask[ci] = ~m;
            }
            __syncthreads();
            // --- INCREMENTAL PUBLISH: chunk ci proposals have final status ---
            if (myc == ci && (cmask[myc] & mybit)) {
                int kb2 = 0;
                for (int c2 = 0; c2 < myc; ++c2) kb2 += __popcll(cmask[c2]);
                kb2 += __popcll(cmask[myc] & (mybit - 1));
                if (kb2 < NUM_PROP_AFTER) {
                    int t0v = (int)rintf(my_s);
                    t0v = max(0, min(t0v, T_LEN - PROP_LEN));
                    __hip_atomic_store(&t0s[kb2], (unsigned int)t0v | 0x80000000u,
                                       __ATOMIC_RELAXED, __HIP_MEMORY_SCOPE_AGENT);
                }
            }
            unsigned long long am = cmask[ci];
            for (int l = 0; l < 64; ++l) {
                if ((am >> l) & 1) {
                    int i = ci * 64 + l;
                    if (tid > i && !mysup) {
                        float ls = ss[i], le = se[i];
                        float inter = fmaxf(fminf(le, my_e) - fmaxf(ls, my_s), 0.0f);
                        float uni = (le - ls) + my_len - inter;
                        if (inter / fmaxf(uni, 1e-6f) > 0.5f) mysup = true;
                    }
                }
            }
            sup[tid] = mysup ? 1 : 0;
            __syncthreads();
        }

        // --- final catch-all publish (suppressed-fill when kept < 256;
        //     alive slots re-published idempotently with identical value) ---
        int kb = 0, kt = 0;
        for (int c2 = 0; c2 < 16; ++c2) {
            int p = __popcll(cmask[c2]);
            kt += p;
            if (c2 < myc) kb += p;
        }
        kb += __popcll(cmask[myc] & (mybit - 1));
        int slot = (cmask[myc] & mybit) ? kb : (kt + (tid - kb));
        if (slot < NUM_PROP_AFTER) {
            int t0v = (int)rintf(my_s);
            t0v = max(0, min(t0v, T_LEN - PROP_LEN));
            __hip_atomic_store(&t0s[slot], (unsigned int)t0v | 0x80000000u,
                               __ATOMIC_RELAXED, __HIP_MEMORY_SCOPE_AGENT);
        }
        asm volatile("s_waitcnt vmcnt(0)" ::: "memory");
        __syncthreads();
    }

    // ===== W fragment in kappa order: Wr[10] = 80 halves of row (s,rl) =====
    uint4 Wr[10];
    {
        const int gate = rl >> 6, unit = rl & 63;
        const int grow = gate * 256 + s * 64 + unit;
        const float* __restrict__ bh = W_hh + grow * HID;
        const float* __restrict__ bx = W_ih + grow * NUM_CH;
#pragma unroll
        for (int j = 0; j < 10; ++j) {
            const int kp = kseg * SEGH + j * 8;  // kappa
            const float* src;
            if (kp < 64) {
                src = bh + s * 64 + kp;                     // own-slice h
            } else if (kp < 128) {
                src = bx + (kp - 64);                       // x
            } else {
                int q = (kp - 128) >> 6, v = (kp - 128) & 63;
                int sp = q + (q >= s ? 1 : 0);
                src = bh + sp * 64 + v;                     // peer-slice h
            }
            float4 f0 = *(const float4*)src;
            float4 f1 = *(const float4*)(src + 4);
            Wr[j] = make_uint4(pack2(f0.x, f0.y), pack2(f0.z, f0.w),
                               pack2(f1.x, f1.y), pack2(f1.z, f1.w));
        }
    }

    // producer role (tid<256): wave aq = seq, lane au = unit of slice s
    const int aq = tid >> 6;
    const int au = tid & 63;
    float bi = 0.f, bf = 0.f, bg = 0.f, bo = 0.f, c_st = 0.f;
    int xt0 = 0;
    if (tid < 256) {
        int u = s * 64 + au;
        bi = b_ih[u] + b_hh[u];
        bf = b_ih[256 + u] + b_hh[256 + u];
        bg = b_ih[512 + u] + b_hh[512 + u];
        bo = b_ih[768 + u] + b_hh[768 + u];
    }

    // gather role (waves 8-13, tid 512..895): lane li, one u64 = 2 tagged words
    const int li = tid - 512;                 // 0..383
    const int q_ = li >> 7;                   // peer index 0..2
    const int rem = li & 127;
    const int gsq = rem >> 5;                 // seq
    const int gu2 = (rem & 31) * 2;           // even unit within peer slice
    const int sp_ = q_ + (q_ >= s ? 1 : 0);   // peer slice
    const int goff = (g * MS + gsq) * HID + sp_ * 64 + gu2;  // even u32 index
    const int gw = (tid >> 6) - 8;            // gather wave id 0..5

    // zero hx (1280 halves) + flags
    ((unsigned short*)hx)[tid] = 0;
    if (tid < 256) ((unsigned short*)hx)[1024 + tid] = 0;
    if (tid < 6) gfl[tid] = 0;

    // producers poll tagged t0s, load x(0) -> kappa [64,128)
    if (tid < 256) {
        const unsigned int* tp = &t0s[g * MS + aq];
        unsigned int tv;
        for (;;) {
            tv = __hip_atomic_load(tp, __ATOMIC_RELAXED, __HIP_MEMORY_SCOPE_AGENT);
            if (tv & 0x80000000u) break;
            __builtin_amdgcn_s_sleep(8);
        }
        xt0 = (int)(tv & 0x7FFFFFFFu);
        hx[aq][64 + au] = (_Float16)data[xt0 * NUM_CH + au];  // x(0)
    }
    __syncthreads();

    for (int t = 0; t < PROP_LEN; ++t) {
        // producers: early x(t+1) issue (lands during the dot)
        float xnext = 0.0f;
        if (tid < 256 && t + 1 < PROP_LEN)
            xnext = data[(xt0 + t + 1) * NUM_CH + au];

        float a0 = 0.f, a1 = 0.f, a2 = 0.f, a3 = 0.f;
#define DOTJ(J)                                                         \
        {                                                               \
            const int hb = kseg * SEGH + (J) * 8;                       \
            uint4 h0 = *(const uint4*)&hx[0][hb];                       \
            uint4 h1 = *(const uint4*)&hx[1][hb];                       \
            uint4 h2 = *(const uint4*)&hx[2][hb];                       \
            uint4 h3 = *(const uint4*)&hx[3][hb];                       \
            uint4 w = Wr[(J)];                                          \
            a0 = dot8f(w, h0, a0);                                      \
            a1 = dot8f(w, h1, a1);                                      \
            a2 = dot8f(w, h2, a2);                                      \
            a3 = dot8f(w, h3, a3);                                      \
        }

        // --- phase 1: local dot (kseg0: all 10; kseg1: first 6) ---
        if (kseg == 0) {
            DOTJ(0) DOTJ(1) DOTJ(2) DOTJ(3) DOTJ(4)
            DOTJ(5) DOTJ(6) DOTJ(7) DOTJ(8) DOTJ(9)
        } else if (kseg == 1) {
            DOTJ(0) DOTJ(1) DOTJ(2) DOTJ(3) DOTJ(4) DOTJ(5)
        }

        // --- gather peer h(t) (waves 8-13), concurrent with local dots ---
        if (t >= 1 && tid >= 512 && tid < 896) {
            const unsigned int tagv = (unsigned int)t;
            const int par = t & 1;
            const unsigned long long* ga =
                (const unsigned long long*)(Hx32 + par * HXPAR + goff);
            unsigned long long v =
                __hip_atomic_load(ga, __ATOMIC_RELAXED, __HIP_MEMORY_SCOPE_AGENT);
            while (__builtin_expect(((unsigned int)v >> 16) != tagv ||
                                        ((unsigned int)(v >> 32) >> 16) != tagv,
                                    0)) {
                __builtin_amdgcn_s_sleep(2);
                v = __hip_atomic_load(ga, __ATOMIC_RELAXED,
                                      __HIP_MEMORY_SCOPE_AGENT);
            }
            unsigned int lo = (unsigned int)v;
            unsigned int hi = (unsigned int)(v >> 32);
            *(unsigned int*)&hx[gsq][128 + q_ * 64 + gu2] =
                (lo & 0xFFFFu) | (hi << 16);
            asm volatile("s_waitcnt lgkmcnt(0)" ::: "memory");
            if ((tid & 63) == 0) gfl[gw] = (unsigned int)t;
        }

        // --- flag wait, then peer dot (kseg >= 1) ---
        if (kseg != 0) {
            if (t >= 1) {
                while (gfl[0] < (unsigned int)t || gfl[1] < (unsigned int)t ||
                       gfl[2] < (unsigned int)t || gfl[3] < (unsigned int)t ||
                       gfl[4] < (unsigned int)t || gfl[5] < (unsigned int)t) {
                    __builtin_amdgcn_s_sleep(1);
                }
                asm volatile("" ::: "memory");
            }
            if (kseg == 1) {
                DOTJ(6) DOTJ(7) DOTJ(8) DOTJ(9)
            } else {
                DOTJ(0) DOTJ(1) DOTJ(2) DOTJ(3) DOTJ(4)
                DOTJ(5) DOTJ(6) DOTJ(7) DOTJ(8) DOTJ(9)
            }
        }
#undef DOTJ

        pp[0][kseg][rl] = a0;
        pp[1][kseg][rl] = a1;
        pp[2][kseg][rl] = a2;
        pp[3][kseg][rl] = a3;
        __syncthreads();  // B1

        const unsigned int tagv = (unsigned int)(t + 1);
        const int par = (t + 1) & 1;
        if (tid < 256) {
            // --- reduce + activation + PAIRED tagged publish + local writes ---
            float si = pp[aq][0][au] + pp[aq][1][au] + pp[aq][2][au] +
                       pp[aq][3][au] + bi;
            float sf = pp[aq][0][64 + au] + pp[aq][1][64 + au] +
                       pp[aq][2][64 + au] + pp[aq][3][64 + au] + bf;
            float sg = pp[aq][0][128 + au] + pp[aq][1][128 + au] +
                       pp[aq][2][128 + au] + pp[aq][3][128 + au] + bg;
            float so = pp[aq][0][192 + au] + pp[aq][1][192 + au] +
                       pp[aq][2][192 + au] + pp[aq][3][192 + au] + bo;
            float gi = fsigmoid(si), gf = fsigmoid(sf);
            float gg = ftanh(sg), go = fsigmoid(so);
            c_st = gf * c_st + gi * gg;
            float h = go * ftanh(c_st);
            HU16 hu;
            hu.h = (_Float16)h;
            unsigned int myw = (tagv << 16) | (unsigned int)hu.u;
            unsigned int pw = __shfl_xor(myw, 1);
            if ((au & 1) == 0) {
                unsigned long long dw =
                    (unsigned long long)myw | ((unsigned long long)pw << 32);
                __hip_atomic_store(
                    (unsigned long long*)&Hx32[par * HXPAR +
                                               (g * MS + aq) * HID + s * 64 + au],
                    dw, __ATOMIC_RELAXED, __HIP_MEMORY_SCOPE_AGENT);
            }
            hx[aq][au] = hu.h;                                  // own-h, kappa [0,64)
            if (t + 1 < PROP_LEN) hx[aq][64 + au] = (_Float16)xnext;  // x(t+1)
        }
        __syncthreads();  // B2
    }

    // final gather: peer h(128) (tag 128, parity 0) for the heads
    if (tid >= 512 && tid < 896) {
        const unsigned int tagv = (unsigned int)PROP_LEN;
        const unsigned long long* ga = (const unsigned long long*)(Hx32 + goff);
        unsigned long long v =
            __hip_atomic_load(ga, __ATOMIC_RELAXED, __HIP_MEMORY_SCOPE_AGENT);
        while (((unsigned int)v >> 16) != tagv ||
               ((unsigned int)(v >> 32) >> 16) != tagv) {
            __builtin_amdgcn_s_sleep(2);
            v = __hip_atomic_load(ga, __ATOMIC_RELAXED, __HIP_MEMORY_SCOPE_AGENT);
        }
        unsigned int lo = (unsigned int)v;
        unsigned int hi = (unsigned int)(v >> 32);
        *(unsigned int*)&hx[gsq][128 + q_ * 64 + gu2] = (lo & 0xFFFFu) | (hi << 16);
    }
    __syncthreads();

    // heads: hx kappa layout: own [0,64), peers q at [128+q*64, ...)
    if (tid < MS * 30) {
        int sq = tid / 30;
        int ml = tid % 30;
        int m = s * 30 + ml;
        const float* Wrow;
        float acc;
        int oidx;
        if (m < NUM_CLS) {
            Wrow = W_cls + m * HID;
            acc = b_cls[m];
            oidx = (g * MS + sq) * NUM_CLS + m;
        } else {
            int mb = m - NUM_CLS;
            Wrow = W_bbox + mb * HID;
            acc = b_bbox[mb];
            oidx = NUM_PROP_AFTER * NUM_CLS + (g * MS + sq) * 2 * NUM_CLS + mb;
        }
        const _Float16* hp = &hx[sq][0];
        for (int k = 0; k < 64; ++k) acc += Wrow[s * 64 + k] * (float)hp[k];
        for (int q2 = 0; q2 < 3; ++q2) {
            int sp2 = q2 + (q2 >= s ? 1 : 0);
            const float* wr = Wrow + sp2 * 64;
            const _Float16* hr = hp + 128 + q2 * 64;
            for (int v2 = 0; v2 < 64; ++v2) acc += wr[v2] * (float)hr[v2];
        }
        out[oidx] = acc;
    }
}

extern "C" void kernel_launch(void* const* d_in, const int* in_sizes, int n_in,
                              void* d_out, int out_size, void* d_ws,
                              size_t ws_size, hipStream_t stream) {
    const float* data = (const float*)d_in[0];     // [8192, 64]
    const float* prop = (const float*)d_in[1];     // [1024, 3]
    const float* W_ih = (const float*)d_in[2];     // [1024, 64]
    const float* W_hh = (const float*)d_in[3];     // [1024, 256]
    const float* b_ih = (const float*)d_in[4];     // [1024]
    const float* b_hh = (const float*)d_in[5];     // [1024]
    const float* W_cls = (const float*)d_in[6];    // [40, 256]
    const float* b_cls = (const float*)d_in[7];    // [40]
    const float* W_bbox = (const float*)d_in[8];   // [80, 256]
    const float* b_bbox = (const float*)d_in[9];   // [80]
    float* out = (float*)d_out;

    // workspace layout (identical to R10/R11/R14/R16)
    unsigned int* t0s = (unsigned int*)d_ws;                   // [0, 1KB) tagged t0s
    unsigned int* Hx32 = (unsigned int*)((char*)d_ws + 4096);  // 512 KB tagged h (2 parities)

    // zero all tags each invocation (graph-captured, replayed per rep)
    hipMemsetAsync(d_ws, 0, 4096 + 2 * HXPAR * 4, stream);

    void* kargs[] = {(void*)&data,  (void*)&prop,   (void*)&W_ih,  (void*)&W_hh,
                     (void*)&b_ih,  (void*)&b_hh,   (void*)&W_cls, (void*)&b_cls,
                     (void*)&W_bbox, (void*)&b_bbox, (void*)&out,  (void*)&t0s,
                     (void*)&Hx32};
    hipLaunchCooperativeKernel((void*)fused_kernel, dim3(NSL * NGRP), dim3(1024),
                               kargs, 0, stream);
}